// Round 13
// baseline (423.532 us; speedup 1.0000x reference)
//
#include <hip/hip_runtime.h>
#include <hip/hip_bf16.h>

#define NN 50000     // nodes
#define NR 4         // relations
#define NE 160000    // edges per relation
#define HD 128       // hidden dim
#define OD 100       // out dim
#define NQ 8192      // queries
#define NB_SCAN 196  // 196*256 >= NN

// merged-prep region sizes (all exact multiples of 256)
#define NB_COUNT 2500   // NR*NE/256
#define NB_CONV  6250   // NN*HD/4/256
#define NB_PREPW 960    // 3*128*640/256

typedef __attribute__((ext_vector_type(8))) short bf16x8;
typedef __attribute__((ext_vector_type(4))) float f32x4;
typedef __attribute__((ext_vector_type(2))) float f32x2;
typedef __attribute__((ext_vector_type(4))) int int4v;

static __device__ __forceinline__ unsigned short f2bf(float f) {
    union { float f; unsigned int u; } v; v.f = f;
    unsigned int u = v.u;
    unsigned int r = u + 0x7FFFu + ((u >> 16) & 1u);   // RNE
    return (unsigned short)(r >> 16);
}
static __device__ __forceinline__ float bflo(unsigned int v) {
    union { unsigned int u; float f; } x; x.u = v << 16; return x.f;
}
static __device__ __forceinline__ float bfhi(unsigned int v) {
    union { unsigned int u; float f; } x; x.u = v & 0xffff0000u; return x.f;
}

// ---------------- merged prep: count_deg | conv_feat | prep_w ----------------

__global__ __launch_bounds__(256) void prep_merged_kernel(
        const int* __restrict__ edge_dst, int* __restrict__ deg,
        const float* __restrict__ feature, unsigned short* __restrict__ h,
        const float* __restrict__ Ws_h, const float* __restrict__ Wr_h,
        const float* __restrict__ Ws_o, const float* __restrict__ Wr_o,
        unsigned short* __restrict__ Wt) {
    const int b = blockIdx.x;
    if (b < NB_COUNT) {
        const int i = b * 256 + threadIdx.x;            // < NR*NE exactly
        const int r = i / NE;
        atomicAdd(&deg[r * NN + edge_dst[i]], 1);
    } else if (b < NB_COUNT + NB_CONV) {
        const int i = ((b - NB_COUNT) * 256 + threadIdx.x) * 4;  // < NN*HD exactly
        h[i + 0] = f2bf(feature[i + 0]);
        h[i + 1] = f2bf(feature[i + 1]);
        h[i + 2] = f2bf(feature[i + 2]);
        h[i + 3] = f2bf(feature[i + 3]);
    } else {
        const int idx = (b - NB_COUNT - NB_CONV) * 256 + threadIdx.x;  // < 3*128*640
        const int l = idx / (128 * 640);
        const int rem = idx % (128 * 640);
        const int c = rem / 640;
        const int k = rem % 640;
        float v = 0.0f;
        if (l < 2) {
            if (k < HD) v = Ws_h[(l * HD + k) * HD + c];
            else {
                int r = (k - HD) >> 7, kk = (k - HD) & 127;
                v = Wr_h[((l * NR + r) * HD + kk) * HD + c];
            }
        } else if (c < OD) {
            if (k < HD) v = Ws_o[k * OD + c];
            else {
                int r = (k - HD) >> 7, kk = (k - HD) & 127;
                v = Wr_o[(r * HD + kk) * OD + c];
            }
        }
        Wt[idx] = f2bf(v);
    }
}

// ---------------- scan ----------------

__global__ __launch_bounds__(256) void scanA_kernel(const int* __restrict__ deg,
                                                    int* __restrict__ excl,
                                                    int* __restrict__ bsum) {
    const int r = blockIdx.x / NB_SCAN;
    const int b = blockIdx.x % NB_SCAN;
    const int tid = threadIdx.x;
    const int idx = b * 256 + tid;
    int v = (idx < NN) ? deg[r * NN + idx] : 0;
    __shared__ int buf[256];
    buf[tid] = v; __syncthreads();
    int sum = v;
    for (int off = 1; off < 256; off <<= 1) {
        int t = (tid >= off) ? buf[tid - off] : 0;
        __syncthreads();
        sum += t; buf[tid] = sum;
        __syncthreads();
    }
    if (idx < NN) excl[r * NN + idx] = sum - v;
    if (tid == 255) bsum[r * NB_SCAN + b] = sum;
}

// scanC with inlined chunk-prefix reduction (replaces scanB)
__global__ __launch_bounds__(256) void scanC_kernel(const int* __restrict__ excl,
                                                    const int* __restrict__ bsum,
                                                    int* __restrict__ row_start,
                                                    int* __restrict__ cursor) {
    const int r = blockIdx.x / NB_SCAN;
    const int b = blockIdx.x % NB_SCAN;
    const int tid = threadIdx.x;
    __shared__ int buf[256];
    // prefix = sum of bsum[r][0..b-1]  (b <= 195 < 256)
    buf[tid] = (tid < b) ? bsum[r * NB_SCAN + tid] : 0;
    __syncthreads();
    for (int off = 128; off > 0; off >>= 1) {
        if (tid < off) buf[tid] += buf[tid + off];
        __syncthreads();
    }
    const int prefix = buf[0];
    const int idx = b * 256 + tid;
    if (idx < NN) {
        int v = excl[r * NN + idx] + prefix;
        row_start[r * (NN + 1) + idx] = v;
        cursor[r * NN + idx] = v;
    }
    if (b == 0 && tid == 0) row_start[r * (NN + 1) + NN] = NE;
}

__global__ __launch_bounds__(256) void fill_csr_kernel(const int* __restrict__ edge_src,
                                                       const int* __restrict__ edge_dst,
                                                       int* __restrict__ cursor,
                                                       int* __restrict__ csr_src) {
    const int i = blockIdx.x * 256 + threadIdx.x;     // < NR*NE exactly
    const int r = i / NE;
    const int dst = edge_dst[i];
    const int pos = atomicAdd(&cursor[r * NN + dst], 1);
    csr_src[r * NE + pos] = edge_src[i];
}

// ---------------- fused: pair-interleaved 8-slot reg-gather + GEMM ----------------
// Block = 512 thr (8 waves), 32 nodes. LDS 40KB: [0,8192) hT ; [8192,40960) agg.
// Phase 0: stage h tile [32][256B] -> LDS (swizzled), 1 x 16B per thread.
// Phase 1: wave w handles nodes 4w..4w+3 as TWO PAIRS; lane-group g (16 lanes
//          x 16B = full 256B h row) = relation g. Per pair: both nodes' 8
//          slot indices (guarded), then A rows 0-3 and B rows 0-3 in flight
//          together (8 rows across 2 nodes); consume A || issue A 4-7;
//          consume B || issue B 4-7; finish + emit both. Packed f32x2
//          accumulate; rare tail for deg > 8; scale by 1/(e-s); one swizzled
//          ds_write_b128 per node. No atomics.
// Phase 2: GEMM [hT | agg](32x640) @ Wt(128x640)^T. Wave w owns 16 cols;
//          B frags kb<4 prefetched pre-barrier; A from LDS (XOR swizzle);
//          20 K-steps, setprio(1) around the MFMA loop.
// Epilogues: XOR-swizzled LDS bounce, coalesced 16B stores.

#define ACC4(CV, VJ)                                                  \
    {                                                                 \
        const unsigned int* vu = (const unsigned int*)&VJ;            \
        CV[0] += (f32x2){bflo(vu[0]), bfhi(vu[0])};                   \
        CV[1] += (f32x2){bflo(vu[1]), bfhi(vu[1])};                   \
        CV[2] += (f32x2){bflo(vu[2]), bfhi(vu[2])};                   \
        CV[3] += (f32x2){bflo(vu[3]), bfhi(vu[3])};                   \
    }

template<int MODE>
__global__ __launch_bounds__(512, 8)
void fused_kernel(const unsigned short* __restrict__ h,
                  const unsigned short* __restrict__ Bt,
                  const int* __restrict__ row_start,
                  const int* __restrict__ csr_src,
                  void* __restrict__ outp, int M) {
    __shared__ __align__(16) char lds[40960];   // [0,8192) hT ; [8192,40960) agg
    const int tid = threadIdx.x;
    const int m0 = blockIdx.x * 32;
    const int lane = tid & 63;
    const int w = tid >> 6;            // 0..7

    // ---- phase 0: stage h tile ----
    {
        const int row = tid >> 4, kb = (tid & 15) * 16;
        int gr = m0 + row; if (gr >= M) gr = M - 1;
        int4v v = *(const int4v*)((const char*)h + (size_t)gr * 256 + kb);
        *(int4v*)(lds + row * 256 + (kb ^ ((row & 7) << 4))) = v;
    }

    // ---- phase 1: pair-interleaved gather ----
    {
        const int g = lane >> 4, li = lane & 15;
        const int* __restrict__ csr = csr_src + (size_t)g * NE;
        const char* hp = (const char*)h + li * 16;
        const int n0 = m0 + (w << 2);
        const int rsB = g * (NN + 1);

        int bnd[5];
#pragma unroll
        for (int i = 0; i < 5; i++) {
            int n = n0 + i; if (n > M) n = M;
            bnd[i] = row_start[rsB + n];
        }

#pragma unroll 1
        for (int p = 0; p < 2; ++p) {
            const int sA = bnd[2 * p],     eA = bnd[2 * p + 1];
            const int sB = bnd[2 * p + 1], eB = bnd[2 * p + 2];

            // slot indices for both nodes (guarded, independent)
            int ja[8], jb[8];
#pragma unroll
            for (int j = 0; j < 8; j++) ja[j] = (sA + j < eA) ? csr[sA + j] : 0;
#pragma unroll
            for (int j = 0; j < 8; j++) jb[j] = (sB + j < eB) ? csr[sB + j] : 0;

            // rows: A slots 0-3 and B slots 0-3 in flight together
            int4v A[4], B[4];
#pragma unroll
            for (int j = 0; j < 4; j++)
                A[j] = (sA + j < eA) ? *(const int4v*)(hp + (size_t)ja[j] * 256) : (int4v){0, 0, 0, 0};
#pragma unroll
            for (int j = 0; j < 4; j++)
                B[j] = (sB + j < eB) ? *(const int4v*)(hp + (size_t)jb[j] * 256) : (int4v){0, 0, 0, 0};

            f32x2 ca[4] = {{0.f, 0.f}, {0.f, 0.f}, {0.f, 0.f}, {0.f, 0.f}};
            f32x2 cb[4] = {{0.f, 0.f}, {0.f, 0.f}, {0.f, 0.f}, {0.f, 0.f}};

            // consume A part1, then reuse A regs for slots 4-7
#pragma unroll
            for (int j = 0; j < 4; j++) ACC4(ca, A[j]);
#pragma unroll
            for (int j = 0; j < 4; j++)
                A[j] = (sA + 4 + j < eA) ? *(const int4v*)(hp + (size_t)ja[4 + j] * 256) : (int4v){0, 0, 0, 0};

            // consume B part1, then reuse B regs for slots 4-7
#pragma unroll
            for (int j = 0; j < 4; j++) ACC4(cb, B[j]);
#pragma unroll
            for (int j = 0; j < 4; j++)
                B[j] = (sB + 4 + j < eB) ? *(const int4v*)(hp + (size_t)jb[4 + j] * 256) : (int4v){0, 0, 0, 0};

            // consume A part2; tail + emit node A
#pragma unroll
            for (int j = 0; j < 4; j++) ACC4(ca, A[j]);
            for (int t = sA + 8; t < eA; ++t) {
                const int src = csr[t];
                const int4v v = *(const int4v*)(hp + (size_t)src * 256);
                ACC4(ca, v);
            }
            {
                const float inv = 1.0f / fmaxf((float)(eA - sA), 1.0f);
                unsigned int p0 = (unsigned int)f2bf(inv * ca[0][0]) | ((unsigned int)f2bf(inv * ca[0][1]) << 16);
                unsigned int p1 = (unsigned int)f2bf(inv * ca[1][0]) | ((unsigned int)f2bf(inv * ca[1][1]) << 16);
                unsigned int p2 = (unsigned int)f2bf(inv * ca[2][0]) | ((unsigned int)f2bf(inv * ca[2][1]) << 16);
                unsigned int p3 = (unsigned int)f2bf(inv * ca[3][0]) | ((unsigned int)f2bf(inv * ca[3][1]) << 16);
                const int row = (w << 2) + 2 * p;
                const int cb0 = g * 256 + li * 16;
                *(int4v*)(lds + 8192 + row * 1024 + (cb0 ^ ((row & 7) << 4))) =
                    (int4v){(int)p0, (int)p1, (int)p2, (int)p3};
            }

            // consume B part2; tail + emit node B
#pragma unroll
            for (int j = 0; j < 4; j++) ACC4(cb, B[j]);
            for (int t = sB + 8; t < eB; ++t) {
                const int src = csr[t];
                const int4v v = *(const int4v*)(hp + (size_t)src * 256);
                ACC4(cb, v);
            }
            {
                const float inv = 1.0f / fmaxf((float)(eB - sB), 1.0f);
                unsigned int p0 = (unsigned int)f2bf(inv * cb[0][0]) | ((unsigned int)f2bf(inv * cb[0][1]) << 16);
                unsigned int p1 = (unsigned int)f2bf(inv * cb[1][0]) | ((unsigned int)f2bf(inv * cb[1][1]) << 16);
                unsigned int p2 = (unsigned int)f2bf(inv * cb[2][0]) | ((unsigned int)f2bf(inv * cb[2][1]) << 16);
                unsigned int p3 = (unsigned int)f2bf(inv * cb[3][0]) | ((unsigned int)f2bf(inv * cb[3][1]) << 16);
                const int row = (w << 2) + 2 * p + 1;
                const int cb0 = g * 256 + li * 16;
                *(int4v*)(lds + 8192 + row * 1024 + (cb0 ^ ((row & 7) << 4))) =
                    (int4v){(int)p0, (int)p1, (int)p2, (int)p3};
            }
        }
    }

    // ---- B-fragment prefetch for kb=0..3 (independent of LDS; hides under barrier) ----
    const int lr = lane & 15;
    const int lg = lane >> 4;
    const char* bB = (const char*)Bt + (size_t)(w * 16 + lr) * 1280;
    bf16x8 bpre[4];
#pragma unroll
    for (int kb = 0; kb < 4; kb++)
        bpre[kb] = *(const bf16x8*)(bB + kb * 64 + lg * 16);

    __syncthreads();

    // ---- phase 2: GEMM; wave w owns output cols w*16..w*16+16 ----
    f32x4 acc[2];
    acc[0] = (f32x4){0.f, 0.f, 0.f, 0.f};
    acc[1] = (f32x4){0.f, 0.f, 0.f, 0.f};

    __builtin_amdgcn_s_setprio(1);
#pragma unroll
    for (int kb = 0; kb < 20; ++kb) {
        const int kByte = kb * 64 + lg * 16;
        bf16x8 bfr = (kb < 4) ? bpre[kb] : *(const bf16x8*)(bB + kByte);
#pragma unroll
        for (int mi = 0; mi < 2; mi++) {
            const int row = mi * 16 + lr;
            int off;
            if (kb < 4) off = row * 256 + (kByte ^ ((row & 7) << 4));
            else        off = 8192 + row * 1024 + ((kByte - 256) ^ ((row & 7) << 4));
            bf16x8 af = *(const bf16x8*)(lds + off);
            acc[mi] = __builtin_amdgcn_mfma_f32_16x16x32_bf16(af, bfr, acc[mi], 0, 0, 0);
        }
    }
    __builtin_amdgcn_s_setprio(0);

    __syncthreads();                        // all A-reads done; reuse LDS as bounce

    if (MODE == 0) {
        // relu -> bf16 tile [32][256B] at lds[0..8192), XOR-swizzled rows
#pragma unroll
        for (int mi = 0; mi < 2; mi++) {
            const int col = w * 16 + lr;
#pragma unroll
            for (int j = 0; j < 4; j++) {
                const int row = mi * 16 + lg * 4 + j;
                *(unsigned short*)(lds + row * 256 + ((col * 2) ^ ((row & 7) << 4))) =
                    f2bf(fmaxf(acc[mi][j], 0.f));
            }
        }
        __syncthreads();
        unsigned short* o = (unsigned short*)outp;
        const int row = tid >> 4, kb = (tid & 15) * 16;
        const int grow = m0 + row;
        if (grow < M)
            *(int4v*)((char*)o + (size_t)grow * 256 + kb) =
                *(const int4v*)(lds + row * 256 + (kb ^ ((row & 7) << 4)));
    } else {
        // f32 tile [32][512B] at lds[0..16384), XOR-swizzled rows
#pragma unroll
        for (int mi = 0; mi < 2; mi++) {
            const int col = w * 16 + lr;
#pragma unroll
            for (int j = 0; j < 4; j++) {
                const int row = mi * 16 + lg * 4 + j;
                *(float*)(lds + row * 512 + ((col * 4) ^ ((row & 7) << 4))) = acc[mi][j];
            }
        }
        __syncthreads();
        float* o = (float*)outp;
#pragma unroll
        for (int i = 0; i < 2; i++) {
            const int c = tid + i * 512;       // 1024 chunks of 16B
            const int row = c >> 5, o16 = (c & 31) * 16;
            const int grow = m0 + row;
            if (grow < M)
                *(int4v*)((char*)o + (size_t)grow * 512 + o16) =
                    *(const int4v*)(lds + row * 512 + (o16 ^ ((row & 7) << 4)));
        }
    }
}

// ---------------- final gather (float4) ----------------

__global__ __launch_bounds__(256) void gather_out_kernel(const float* __restrict__ hOut,
                                                         const int* __restrict__ head,
                                                         const int* __restrict__ tail,
                                                         float* __restrict__ out) {
    const int gid = blockIdx.x * 256 + threadIdx.x;
    const int q = gid >> 5, c = gid & 31;
    if (q >= 2 * NQ || c >= 25) return;
    const int node = (q < NQ) ? head[q] : tail[q - NQ];
    f32x4 v = *(const f32x4*)(hOut + (size_t)node * 128 + c * 4);
    *(f32x4*)(out + (size_t)q * OD + c * 4) = v;
}

// ---------------- launch ----------------

extern "C" void kernel_launch(void* const* d_in, const int* in_sizes, int n_in,
                              void* d_out, int out_size, void* d_ws, size_t ws_size,
                              hipStream_t stream) {
    const float* feature = (const float*)d_in[0];
    const float* Wr_h    = (const float*)d_in[1];   // [2][4][128][128]
    const float* Ws_h    = (const float*)d_in[2];   // [2][128][128]
    const float* Wr_o    = (const float*)d_in[3];   // [4][128][100]
    const float* Ws_o    = (const float*)d_in[4];   // [128][100]
    const int* edge_src  = (const int*)d_in[5];
    const int* edge_dst  = (const int*)d_in[6];
    const int* head_idx  = (const int*)d_in[7];
    const int* tail_idx  = (const int*)d_in[8];
    float* out = (float*)d_out;

    char* ws = (char*)d_ws;
    size_t off = 0;
    auto alloc = [&](size_t bytes) -> void* {
        void* p = ws + off;
        off += (bytes + 255) & ~(size_t)255;
        return p;
    };
    unsigned short* hA   = (unsigned short*)alloc((size_t)NN * HD * 2);
    unsigned short* hB   = (unsigned short*)alloc((size_t)NN * HD * 2);
    float*          hOut = (float*)alloc((size_t)NN * 128 * 4);
    unsigned short* Wt   = (unsigned short*)alloc((size_t)3 * 128 * 640 * 2);
    int*            deg  = (int*)alloc((size_t)NR * NN * 4);
    int*            rowS = (int*)alloc((size_t)NR * (NN + 1) * 4);
    int*            curs = (int*)alloc((size_t)NR * NN * 4);
    int*            csrS = (int*)alloc((size_t)NR * NE * 4 + 64);
    int*            excl = (int*)alloc((size_t)NR * NN * 4);
    int*            bsum = (int*)alloc((size_t)NR * NB_SCAN * 4);
    (void)ws_size;

    // prep: zero deg, then merged {count_deg | conv_feat | prep_w}
    hipMemsetAsync(deg, 0, (size_t)NR * NN * 4, stream);
    prep_merged_kernel<<<NB_COUNT + NB_CONV + NB_PREPW, 256, 0, stream>>>(
        edge_dst, deg, feature, hA, Ws_h, Wr_h, Ws_o, Wr_o, Wt);
    scanA_kernel<<<NR * NB_SCAN, 256, 0, stream>>>(deg, excl, bsum);
    scanC_kernel<<<NR * NB_SCAN, 256, 0, stream>>>(excl, bsum, rowS, curs);
    fill_csr_kernel<<<NB_COUNT, 256, 0, stream>>>(edge_src, edge_dst, curs, csrS);

    const int fblocks = (NN + 31) / 32;   // 1563
    unsigned short* WtH0 = Wt;
    unsigned short* WtH1 = Wt + 128 * 640;
    unsigned short* WtO  = Wt + 2 * 128 * 640;

    fused_kernel<0><<<fblocks, 512, 0, stream>>>(hA, WtH0, rowS, csrS, hB, NN);
    fused_kernel<0><<<fblocks, 512, 0, stream>>>(hB, WtH1, rowS, csrS, hA, NN);
    fused_kernel<1><<<fblocks, 512, 0, stream>>>(hA, WtO,  rowS, csrS, hOut, NN);

    gather_out_kernel<<<(2 * NQ * 32 + 255) / 256, 256, 0, stream>>>(hOut, head_idx, tail_idx, out);
}

// Round 14
// 261.912 us; speedup vs baseline: 1.6171x; 1.6171x over previous
//
#include <hip/hip_runtime.h>
#include <hip/hip_bf16.h>

#define NN 50000     // nodes
#define NR 4         // relations
#define NE 160000    // edges per relation
#define HD 128       // hidden dim
#define OD 100       // out dim
#define NQ 8192      // queries
#define NB_SCAN 196  // 196*256 >= NN

// merged-prep region sizes (all exact multiples of 256)
#define NB_COUNT 2500   // NR*NE/256
#define NB_CONV  6250   // NN*HD/4/256
#define NB_PREPW 960    // 3*128*640/256

typedef __attribute__((ext_vector_type(8))) short bf16x8;
typedef __attribute__((ext_vector_type(4))) float f32x4;
typedef __attribute__((ext_vector_type(2))) float f32x2;
typedef __attribute__((ext_vector_type(4))) int int4v;

static __device__ __forceinline__ unsigned short f2bf(float f) {
    union { float f; unsigned int u; } v; v.f = f;
    unsigned int u = v.u;
    unsigned int r = u + 0x7FFFu + ((u >> 16) & 1u);   // RNE
    return (unsigned short)(r >> 16);
}
static __device__ __forceinline__ float bflo(unsigned int v) {
    union { unsigned int u; float f; } x; x.u = v << 16; return x.f;
}
static __device__ __forceinline__ float bfhi(unsigned int v) {
    union { unsigned int u; float f; } x; x.u = v & 0xffff0000u; return x.f;
}

// ---------------- merged prep: count_deg | conv_feat | prep_w ----------------

__global__ __launch_bounds__(256) void prep_merged_kernel(
        const int* __restrict__ edge_dst, int* __restrict__ deg,
        const float* __restrict__ feature, unsigned short* __restrict__ h,
        const float* __restrict__ Ws_h, const float* __restrict__ Wr_h,
        const float* __restrict__ Ws_o, const float* __restrict__ Wr_o,
        unsigned short* __restrict__ Wt) {
    const int b = blockIdx.x;
    if (b < NB_COUNT) {
        const int i = b * 256 + threadIdx.x;            // < NR*NE exactly
        const int r = i / NE;
        atomicAdd(&deg[r * NN + edge_dst[i]], 1);
    } else if (b < NB_COUNT + NB_CONV) {
        const int i = ((b - NB_COUNT) * 256 + threadIdx.x) * 4;  // < NN*HD exactly
        h[i + 0] = f2bf(feature[i + 0]);
        h[i + 1] = f2bf(feature[i + 1]);
        h[i + 2] = f2bf(feature[i + 2]);
        h[i + 3] = f2bf(feature[i + 3]);
    } else {
        const int idx = (b - NB_COUNT - NB_CONV) * 256 + threadIdx.x;  // < 3*128*640
        const int l = idx / (128 * 640);
        const int rem = idx % (128 * 640);
        const int c = rem / 640;
        const int k = rem % 640;
        float v = 0.0f;
        if (l < 2) {
            if (k < HD) v = Ws_h[(l * HD + k) * HD + c];
            else {
                int r = (k - HD) >> 7, kk = (k - HD) & 127;
                v = Wr_h[((l * NR + r) * HD + kk) * HD + c];
            }
        } else if (c < OD) {
            if (k < HD) v = Ws_o[k * OD + c];
            else {
                int r = (k - HD) >> 7, kk = (k - HD) & 127;
                v = Wr_o[(r * HD + kk) * OD + c];
            }
        }
        Wt[idx] = f2bf(v);
    }
}

// ---------------- scan ----------------

__global__ __launch_bounds__(256) void scanA_kernel(const int* __restrict__ deg,
                                                    int* __restrict__ excl,
                                                    int* __restrict__ bsum) {
    const int r = blockIdx.x / NB_SCAN;
    const int b = blockIdx.x % NB_SCAN;
    const int tid = threadIdx.x;
    const int idx = b * 256 + tid;
    int v = (idx < NN) ? deg[r * NN + idx] : 0;
    __shared__ int buf[256];
    buf[tid] = v; __syncthreads();
    int sum = v;
    for (int off = 1; off < 256; off <<= 1) {
        int t = (tid >= off) ? buf[tid - off] : 0;
        __syncthreads();
        sum += t; buf[tid] = sum;
        __syncthreads();
    }
    if (idx < NN) excl[r * NN + idx] = sum - v;
    if (tid == 255) bsum[r * NB_SCAN + b] = sum;
}

// scanC with inlined chunk-prefix reduction (replaces scanB)
__global__ __launch_bounds__(256) void scanC_kernel(const int* __restrict__ excl,
                                                    const int* __restrict__ bsum,
                                                    int* __restrict__ row_start,
                                                    int* __restrict__ cursor) {
    const int r = blockIdx.x / NB_SCAN;
    const int b = blockIdx.x % NB_SCAN;
    const int tid = threadIdx.x;
    __shared__ int buf[256];
    // prefix = sum of bsum[r][0..b-1]  (b <= 195 < 256)
    buf[tid] = (tid < b) ? bsum[r * NB_SCAN + tid] : 0;
    __syncthreads();
    for (int off = 128; off > 0; off >>= 1) {
        if (tid < off) buf[tid] += buf[tid + off];
        __syncthreads();
    }
    const int prefix = buf[0];
    const int idx = b * 256 + tid;
    if (idx < NN) {
        int v = excl[r * NN + idx] + prefix;
        row_start[r * (NN + 1) + idx] = v;
        cursor[r * NN + idx] = v;
    }
    if (b == 0 && tid == 0) row_start[r * (NN + 1) + NN] = NE;
}

__global__ __launch_bounds__(256) void fill_csr_kernel(const int* __restrict__ edge_src,
                                                       const int* __restrict__ edge_dst,
                                                       int* __restrict__ cursor,
                                                       int* __restrict__ csr_src) {
    const int i = blockIdx.x * 256 + threadIdx.x;     // < NR*NE exactly
    const int r = i / NE;
    const int dst = edge_dst[i];
    const int pos = atomicAdd(&cursor[r * NN + dst], 1);
    csr_src[r * NE + pos] = edge_src[i];
}

// ---------------- fused: 8-slot batched reg-gather + GEMM ----------------
// Block = 512 thr (8 waves), 32 nodes. LDS 40KB: [0,8192) hT ; [8192,40960) agg.
// Phase 0: stage h tile [32][256B] -> LDS (swizzled), 1 x 16B per thread.
// Phase 1: wave w handles nodes 4w..4w+3; lane-group g (16 lanes x 16B = full
//          256B h row) = relation g. FOUR EXPLICIT NODE BODIES, all named
//          scalars (no runtime-indexed arrays -> no scratch); per node: 8
//          slot indices + 8 h-rows batched (guarded, independent); packed
//          f32x2 accumulate; rare tail for deg > 8. Scale by 1/(e-s); one
//          swizzled ds_write_b128 per node. No atomics.
// Phase 2: GEMM [hT | agg](32x640) @ Wt(128x640)^T. Wave w owns 16 cols;
//          B frags kb<4 prefetched pre-barrier; A from LDS (XOR swizzle);
//          20 K-steps, setprio(1) around the MFMA loop.
// Epilogues: XOR-swizzled LDS bounce (conflict-free), coalesced 16B stores.

#define ACCW(CV, VJ)                                                  \
    {                                                                 \
        const unsigned int* vu_ = (const unsigned int*)&VJ;           \
        CV##0 += (f32x2){bflo(vu_[0]), bfhi(vu_[0])};                 \
        CV##1 += (f32x2){bflo(vu_[1]), bfhi(vu_[1])};                 \
        CV##2 += (f32x2){bflo(vu_[2]), bfhi(vu_[2])};                 \
        CV##3 += (f32x2){bflo(vu_[3]), bfhi(vu_[3])};                 \
    }

#define GATHER_NODE(S, E, RI)                                                          \
    {                                                                                  \
        const int s_ = (S), e_ = (E);                                                  \
        int i0_ = (s_ + 0 < e_) ? csr[s_ + 0] : 0;                                     \
        int i1_ = (s_ + 1 < e_) ? csr[s_ + 1] : 0;                                     \
        int i2_ = (s_ + 2 < e_) ? csr[s_ + 2] : 0;                                     \
        int i3_ = (s_ + 3 < e_) ? csr[s_ + 3] : 0;                                     \
        int i4_ = (s_ + 4 < e_) ? csr[s_ + 4] : 0;                                     \
        int i5_ = (s_ + 5 < e_) ? csr[s_ + 5] : 0;                                     \
        int i6_ = (s_ + 6 < e_) ? csr[s_ + 6] : 0;                                     \
        int i7_ = (s_ + 7 < e_) ? csr[s_ + 7] : 0;                                     \
        int4v z_ = {0, 0, 0, 0};                                                       \
        int4v w0_ = (s_ + 0 < e_) ? *(const int4v*)(hp + (size_t)i0_ * 256) : z_;      \
        int4v w1_ = (s_ + 1 < e_) ? *(const int4v*)(hp + (size_t)i1_ * 256) : z_;      \
        int4v w2_ = (s_ + 2 < e_) ? *(const int4v*)(hp + (size_t)i2_ * 256) : z_;      \
        int4v w3_ = (s_ + 3 < e_) ? *(const int4v*)(hp + (size_t)i3_ * 256) : z_;      \
        int4v w4_ = (s_ + 4 < e_) ? *(const int4v*)(hp + (size_t)i4_ * 256) : z_;      \
        int4v w5_ = (s_ + 5 < e_) ? *(const int4v*)(hp + (size_t)i5_ * 256) : z_;      \
        int4v w6_ = (s_ + 6 < e_) ? *(const int4v*)(hp + (size_t)i6_ * 256) : z_;      \
        int4v w7_ = (s_ + 7 < e_) ? *(const int4v*)(hp + (size_t)i7_ * 256) : z_;      \
        f32x2 c0 = {0.f, 0.f}, c1 = {0.f, 0.f}, c2 = {0.f, 0.f}, c3 = {0.f, 0.f};      \
        ACCW(c, w0_) ACCW(c, w1_) ACCW(c, w2_) ACCW(c, w3_)                            \
        ACCW(c, w4_) ACCW(c, w5_) ACCW(c, w6_) ACCW(c, w7_)                            \
        for (int t_ = s_ + 8; t_ < e_; ++t_) {                                         \
            const int src_ = csr[t_];                                                  \
            const int4v v_ = *(const int4v*)(hp + (size_t)src_ * 256);                 \
            ACCW(c, v_)                                                                \
        }                                                                              \
        const float inv_ = 1.0f / fmaxf((float)(e_ - s_), 1.0f);                       \
        unsigned int p0_ = (unsigned int)f2bf(inv_ * c0[0]) |                          \
                           ((unsigned int)f2bf(inv_ * c0[1]) << 16);                   \
        unsigned int p1_ = (unsigned int)f2bf(inv_ * c1[0]) |                          \
                           ((unsigned int)f2bf(inv_ * c1[1]) << 16);                   \
        unsigned int p2_ = (unsigned int)f2bf(inv_ * c2[0]) |                          \
                           ((unsigned int)f2bf(inv_ * c2[1]) << 16);                   \
        unsigned int p3_ = (unsigned int)f2bf(inv_ * c3[0]) |                          \
                           ((unsigned int)f2bf(inv_ * c3[1]) << 16);                   \
        const int row_ = (w << 2) + (RI);                                              \
        *(int4v*)(lds + 8192 + row_ * 1024 + (cbase ^ ((row_ & 7) << 4))) =            \
            (int4v){(int)p0_, (int)p1_, (int)p2_, (int)p3_};                           \
    }

template<int MODE>
__global__ __launch_bounds__(512, 8)
void fused_kernel(const unsigned short* __restrict__ h,
                  const unsigned short* __restrict__ Bt,
                  const int* __restrict__ row_start,
                  const int* __restrict__ csr_src,
                  void* __restrict__ outp, int M) {
    __shared__ __align__(16) char lds[40960];   // [0,8192) hT ; [8192,40960) agg
    const int tid = threadIdx.x;
    const int m0 = blockIdx.x * 32;
    const int lane = tid & 63;
    const int w = tid >> 6;            // 0..7

    // ---- phase 0: stage h tile ----
    {
        const int row = tid >> 4, kb = (tid & 15) * 16;
        int gr = m0 + row; if (gr >= M) gr = M - 1;
        int4v v = *(const int4v*)((const char*)h + (size_t)gr * 256 + kb);
        *(int4v*)(lds + row * 256 + (kb ^ ((row & 7) << 4))) = v;
    }

    // ---- phase 1: gather, 4 explicit node bodies ----
    {
        const int g = lane >> 4, li = lane & 15;
        const int* __restrict__ csr = csr_src + (size_t)g * NE;
        const char* hp = (const char*)h + li * 16;
        const int n0 = m0 + (w << 2);
        const int rsB = g * (NN + 1);
        const int cbase = g * 256 + li * 16;

        int nc = M - n0;                     // clamp helper (M=50000, n0 multiple of 4)
        const int b0 = row_start[rsB + n0];
        const int b1 = row_start[rsB + n0 + (nc > 1 ? 1 : nc < 1 ? 0 : 1)];
        const int b1c = (nc >= 1) ? row_start[rsB + n0 + 1] : b0;
        const int b2c = (nc >= 2) ? row_start[rsB + n0 + 2] : b1c;
        const int b3c = (nc >= 3) ? row_start[rsB + n0 + 3] : b2c;
        const int b4c = (nc >= 4) ? row_start[rsB + n0 + 4] : b3c;
        (void)b1;

        GATHER_NODE(b0,  b1c, 0)
        GATHER_NODE(b1c, b2c, 1)
        GATHER_NODE(b2c, b3c, 2)
        GATHER_NODE(b3c, b4c, 3)
    }

    // ---- B-fragment prefetch for kb=0..3 (independent of LDS; hides under barrier) ----
    const int lr = lane & 15;
    const int lg = lane >> 4;
    const char* bB = (const char*)Bt + (size_t)(w * 16 + lr) * 1280;
    bf16x8 bpre[4];
#pragma unroll
    for (int kb = 0; kb < 4; kb++)
        bpre[kb] = *(const bf16x8*)(bB + kb * 64 + lg * 16);

    __syncthreads();

    // ---- phase 2: GEMM; wave w owns output cols w*16..w*16+16 ----
    f32x4 acc[2];
    acc[0] = (f32x4){0.f, 0.f, 0.f, 0.f};
    acc[1] = (f32x4){0.f, 0.f, 0.f, 0.f};

    __builtin_amdgcn_s_setprio(1);
#pragma unroll
    for (int kb = 0; kb < 20; ++kb) {
        const int kByte = kb * 64 + lg * 16;
        bf16x8 bfr = (kb < 4) ? bpre[kb] : *(const bf16x8*)(bB + kByte);
#pragma unroll
        for (int mi = 0; mi < 2; mi++) {
            const int row = mi * 16 + lr;
            int off;
            if (kb < 4) off = row * 256 + (kByte ^ ((row & 7) << 4));
            else        off = 8192 + row * 1024 + ((kByte - 256) ^ ((row & 7) << 4));
            bf16x8 af = *(const bf16x8*)(lds + off);
            acc[mi] = __builtin_amdgcn_mfma_f32_16x16x32_bf16(af, bfr, acc[mi], 0, 0, 0);
        }
    }
    __builtin_amdgcn_s_setprio(0);

    __syncthreads();                        // all A-reads done; reuse LDS as bounce

    if (MODE == 0) {
        // relu -> bf16 tile [32][256B] at lds[0..8192), XOR-swizzled rows
#pragma unroll
        for (int mi = 0; mi < 2; mi++) {
            const int col = w * 16 + lr;
#pragma unroll
            for (int j = 0; j < 4; j++) {
                const int row = mi * 16 + lg * 4 + j;
                *(unsigned short*)(lds + row * 256 + ((col * 2) ^ ((row & 7) << 4))) =
                    f2bf(fmaxf(acc[mi][j], 0.f));
            }
        }
        __syncthreads();
        unsigned short* o = (unsigned short*)outp;
        const int row = tid >> 4, kb = (tid & 15) * 16;
        const int grow = m0 + row;
        if (grow < M)
            *(int4v*)((char*)o + (size_t)grow * 256 + kb) =
                *(const int4v*)(lds + row * 256 + (kb ^ ((row & 7) << 4)));
    } else {
        // f32 tile [32][512B] at lds[0..16384), XOR-swizzled rows
#pragma unroll
        for (int mi = 0; mi < 2; mi++) {
            const int col = w * 16 + lr;
#pragma unroll
            for (int j = 0; j < 4; j++) {
                const int row = mi * 16 + lg * 4 + j;
                *(float*)(lds + row * 512 + ((col * 4) ^ ((row & 7) << 4))) = acc[mi][j];
            }
        }
        __syncthreads();
        float* o = (float*)outp;
#pragma unroll
        for (int i = 0; i < 2; i++) {
            const int c = tid + i * 512;       // 1024 chunks of 16B
            const int row = c >> 5, o16 = (c & 31) * 16;
            const int grow = m0 + row;
            if (grow < M)
                *(int4v*)((char*)o + (size_t)grow * 512 + o16) =
                    *(const int4v*)(lds + row * 512 + (o16 ^ ((row & 7) << 4)));
        }
    }
}

// ---------------- final gather (float4) ----------------

__global__ __launch_bounds__(256) void gather_out_kernel(const float* __restrict__ hOut,
                                                         const int* __restrict__ head,
                                                         const int* __restrict__ tail,
                                                         float* __restrict__ out) {
    const int gid = blockIdx.x * 256 + threadIdx.x;
    const int q = gid >> 5, c = gid & 31;
    if (q >= 2 * NQ || c >= 25) return;
    const int node = (q < NQ) ? head[q] : tail[q - NQ];
    f32x4 v = *(const f32x4*)(hOut + (size_t)node * 128 + c * 4);
    *(f32x4*)(out + (size_t)q * OD + c * 4) = v;
}

// ---------------- launch ----------------

extern "C" void kernel_launch(void* const* d_in, const int* in_sizes, int n_in,
                              void* d_out, int out_size, void* d_ws, size_t ws_size,
                              hipStream_t stream) {
    const float* feature = (const float*)d_in[0];
    const float* Wr_h    = (const float*)d_in[1];   // [2][4][128][128]
    const float* Ws_h    = (const float*)d_in[2];   // [2][128][128]
    const float* Wr_o    = (const float*)d_in[3];   // [4][128][100]
    const float* Ws_o    = (const float*)d_in[4];   // [128][100]
    const int* edge_src  = (const int*)d_in[5];
    const int* edge_dst  = (const int*)d_in[6];
    const int* head_idx  = (const int*)d_in[7];
    const int* tail_idx  = (const int*)d_in[8];
    float* out = (float*)d_out;

    char* ws = (char*)d_ws;
    size_t off = 0;
    auto alloc = [&](size_t bytes) -> void* {
        void* p = ws + off;
        off += (bytes + 255) & ~(size_t)255;
        return p;
    };
    unsigned short* hA   = (unsigned short*)alloc((size_t)NN * HD * 2);
    unsigned short* hB   = (unsigned short*)alloc((size_t)NN * HD * 2);
    float*          hOut = (float*)alloc((size_t)NN * 128 * 4);
    unsigned short* Wt   = (unsigned short*)alloc((size_t)3 * 128 * 640 * 2);
    int*            deg  = (int*)alloc((size_t)NR * NN * 4);
    int*            rowS = (int*)alloc((size_t)NR * (NN + 1) * 4);
    int*            curs = (int*)alloc((size_t)NR * NN * 4);
    int*            csrS = (int*)alloc((size_t)NR * NE * 4 + 64);
    int*            excl = (int*)alloc((size_t)NR * NN * 4);
    int*            bsum = (int*)alloc((size_t)NR * NB_SCAN * 4);
    (void)ws_size;

    // prep: zero deg, then merged {count_deg | conv_feat | prep_w}
    hipMemsetAsync(deg, 0, (size_t)NR * NN * 4, stream);
    prep_merged_kernel<<<NB_COUNT + NB_CONV + NB_PREPW, 256, 0, stream>>>(
        edge_dst, deg, feature, hA, Ws_h, Wr_h, Ws_o, Wr_o, Wt);
    scanA_kernel<<<NR * NB_SCAN, 256, 0, stream>>>(deg, excl, bsum);
    scanC_kernel<<<NR * NB_SCAN, 256, 0, stream>>>(excl, bsum, rowS, curs);
    fill_csr_kernel<<<NB_COUNT, 256, 0, stream>>>(edge_src, edge_dst, curs, csrS);

    const int fblocks = (NN + 31) / 32;   // 1563
    unsigned short* WtH0 = Wt;
    unsigned short* WtH1 = Wt + 128 * 640;
    unsigned short* WtO  = Wt + 2 * 128 * 640;

    fused_kernel<0><<<fblocks, 512, 0, stream>>>(hA, WtH0, rowS, csrS, hB, NN);
    fused_kernel<0><<<fblocks, 512, 0, stream>>>(hB, WtH1, rowS, csrS, hA, NN);
    fused_kernel<1><<<fblocks, 512, 0, stream>>>(hA, WtO,  rowS, csrS, hOut, NN);

    gather_out_kernel<<<(2 * NQ * 32 + 255) / 256, 256, 0, stream>>>(hOut, head_idx, tail_idx, out);
}

// Round 15
// 252.088 us; speedup vs baseline: 1.6801x; 1.0390x over previous
//
#include <hip/hip_runtime.h>
#include <hip/hip_bf16.h>

#define NN 50000     // nodes
#define NR 4         // relations
#define NE 160000    // edges per relation
#define HD 128       // hidden dim
#define OD 100       // out dim
#define NQ 8192      // queries
#define NB_SCAN 196  // 196*256 >= NN

// merged-prep region sizes (all exact multiples of 256)
#define NB_COUNT 2500   // NR*NE/256
#define NB_CONV  6250   // NN*HD/4/256
#define NB_PREPW 960    // 3*128*640/256

typedef __attribute__((ext_vector_type(8))) short bf16x8;
typedef __attribute__((ext_vector_type(4))) float f32x4;
typedef __attribute__((ext_vector_type(2))) float f32x2;
typedef __attribute__((ext_vector_type(4))) int int4v;

static __device__ __forceinline__ unsigned short f2bf(float f) {
    union { float f; unsigned int u; } v; v.f = f;
    unsigned int u = v.u;
    unsigned int r = u + 0x7FFFu + ((u >> 16) & 1u);   // RNE
    return (unsigned short)(r >> 16);
}
static __device__ __forceinline__ float bflo(unsigned int v) {
    union { unsigned int u; float f; } x; x.u = v << 16; return x.f;
}
static __device__ __forceinline__ float bfhi(unsigned int v) {
    union { unsigned int u; float f; } x; x.u = v & 0xffff0000u; return x.f;
}

// ---------------- merged prep: count_deg | conv_feat | prep_w ----------------

__global__ __launch_bounds__(256) void prep_merged_kernel(
        const int* __restrict__ edge_dst, int* __restrict__ deg,
        const float* __restrict__ feature, unsigned short* __restrict__ h,
        const float* __restrict__ Ws_h, const float* __restrict__ Wr_h,
        const float* __restrict__ Ws_o, const float* __restrict__ Wr_o,
        unsigned short* __restrict__ Wt) {
    const int b = blockIdx.x;
    if (b < NB_COUNT) {
        const int i = b * 256 + threadIdx.x;            // < NR*NE exactly
        const int r = i / NE;
        atomicAdd(&deg[r * NN + edge_dst[i]], 1);
    } else if (b < NB_COUNT + NB_CONV) {
        const int i = ((b - NB_COUNT) * 256 + threadIdx.x) * 4;  // < NN*HD exactly
        h[i + 0] = f2bf(feature[i + 0]);
        h[i + 1] = f2bf(feature[i + 1]);
        h[i + 2] = f2bf(feature[i + 2]);
        h[i + 3] = f2bf(feature[i + 3]);
    } else {
        const int idx = (b - NB_COUNT - NB_CONV) * 256 + threadIdx.x;  // < 3*128*640
        const int l = idx / (128 * 640);
        const int rem = idx % (128 * 640);
        const int c = rem / 640;
        const int k = rem % 640;
        float v = 0.0f;
        if (l < 2) {
            if (k < HD) v = Ws_h[(l * HD + k) * HD + c];
            else {
                int r = (k - HD) >> 7, kk = (k - HD) & 127;
                v = Wr_h[((l * NR + r) * HD + kk) * HD + c];
            }
        } else if (c < OD) {
            if (k < HD) v = Ws_o[k * OD + c];
            else {
                int r = (k - HD) >> 7, kk = (k - HD) & 127;
                v = Wr_o[(r * HD + kk) * OD + c];
            }
        }
        Wt[idx] = f2bf(v);
    }
}

// ---------------- scan ----------------

__global__ __launch_bounds__(256) void scanA_kernel(const int* __restrict__ deg,
                                                    int* __restrict__ excl,
                                                    int* __restrict__ bsum) {
    const int r = blockIdx.x / NB_SCAN;
    const int b = blockIdx.x % NB_SCAN;
    const int tid = threadIdx.x;
    const int idx = b * 256 + tid;
    int v = (idx < NN) ? deg[r * NN + idx] : 0;
    __shared__ int buf[256];
    buf[tid] = v; __syncthreads();
    int sum = v;
    for (int off = 1; off < 256; off <<= 1) {
        int t = (tid >= off) ? buf[tid - off] : 0;
        __syncthreads();
        sum += t; buf[tid] = sum;
        __syncthreads();
    }
    if (idx < NN) excl[r * NN + idx] = sum - v;
    if (tid == 255) bsum[r * NB_SCAN + b] = sum;
}

// scanC with inlined chunk-prefix reduction (replaces scanB)
__global__ __launch_bounds__(256) void scanC_kernel(const int* __restrict__ excl,
                                                    const int* __restrict__ bsum,
                                                    int* __restrict__ row_start,
                                                    int* __restrict__ cursor) {
    const int r = blockIdx.x / NB_SCAN;
    const int b = blockIdx.x % NB_SCAN;
    const int tid = threadIdx.x;
    __shared__ int buf[256];
    // prefix = sum of bsum[r][0..b-1]  (b <= 195 < 256)
    buf[tid] = (tid < b) ? bsum[r * NB_SCAN + tid] : 0;
    __syncthreads();
    for (int off = 128; off > 0; off >>= 1) {
        if (tid < off) buf[tid] += buf[tid + off];
        __syncthreads();
    }
    const int prefix = buf[0];
    const int idx = b * 256 + tid;
    if (idx < NN) {
        int v = excl[r * NN + idx] + prefix;
        row_start[r * (NN + 1) + idx] = v;
        cursor[r * NN + idx] = v;
    }
    if (b == 0 && tid == 0) row_start[r * (NN + 1) + NN] = NE;
}

__global__ __launch_bounds__(256) void fill_csr_kernel(const int* __restrict__ edge_src,
                                                       const int* __restrict__ edge_dst,
                                                       int* __restrict__ cursor,
                                                       int* __restrict__ csr_src) {
    const int i = blockIdx.x * 256 + threadIdx.x;     // < NR*NE exactly
    const int r = i / NE;
    const int dst = edge_dst[i];
    const int pos = atomicAdd(&cursor[r * NN + dst], 1);
    csr_src[r * NE + pos] = edge_src[i];
}

// ---------------- fused: 8-slot batched reg-gather + GEMM ----------------
// Block = 512 thr (8 waves), 32 nodes. LDS 40KB: [0,8192) hT ; [8192,40960) agg.
// Phase 0: stage h tile [32][256B] -> LDS (swizzled), 1 x 16B per thread.
// Phase 1: wave w handles nodes 4w..4w+3; lane-group g (16 lanes x 16B = full
//          256B h row) = relation g. Per node: 8 slot indices + 8 h-rows
//          batched (guarded, independent); sched_barrier(0) after the load
//          batch FORCES all 8 rows in flight (deep MLP — without it the
//          allocator serializes into 2-3 live rows, VGPR_Count=32 evidence);
//          packed f32x2 accumulate; rare tail for deg > 8.
//          Scale by 1/(e-s); one swizzled ds_write_b128 per node. No atomics.
// Phase 2: GEMM [hT | agg](32x640) @ Wt(128x640)^T. Wave w owns 16 cols;
//          B frags kb<4 prefetched pre-barrier; A from LDS (XOR swizzle);
//          20 K-steps, setprio(1) around the MFMA loop.
// Epilogues: XOR-swizzled LDS bounce (conflict-free), coalesced 16B stores.

template<int MODE>
__global__ __launch_bounds__(512, 8)
void fused_kernel(const unsigned short* __restrict__ h,
                  const unsigned short* __restrict__ Bt,
                  const int* __restrict__ row_start,
                  const int* __restrict__ csr_src,
                  void* __restrict__ outp, int M) {
    __shared__ __align__(16) char lds[40960];   // [0,8192) hT ; [8192,40960) agg
    const int tid = threadIdx.x;
    const int m0 = blockIdx.x * 32;
    const int lane = tid & 63;
    const int w = tid >> 6;            // 0..7

    // ---- phase 0: stage h tile ----
    {
        const int row = tid >> 4, kb = (tid & 15) * 16;
        int gr = m0 + row; if (gr >= M) gr = M - 1;
        int4v v = *(const int4v*)((const char*)h + (size_t)gr * 256 + kb);
        *(int4v*)(lds + row * 256 + (kb ^ ((row & 7) << 4))) = v;
    }

    // ---- phase 1: 8-slot batched gather ----
    {
        const int g = lane >> 4, li = lane & 15;
        const int* __restrict__ csr = csr_src + (size_t)g * NE;
        const char* hp = (const char*)h + li * 16;
        const int n0 = m0 + (w << 2);
        const int rsB = g * (NN + 1);

        int bnd[5];
#pragma unroll
        for (int i = 0; i < 5; i++) {
            int n = n0 + i; if (n > M) n = M;
            bnd[i] = row_start[rsB + n];
        }

#pragma unroll 1
        for (int i = 0; i < 4; ++i) {
            const int s = bnd[i], e = bnd[i + 1];

            // batch 1: all 8 slot indices (independent, guarded)
            int sj[8];
#pragma unroll
            for (int j = 0; j < 8; j++) sj[j] = (s + j < e) ? csr[s + j] : 0;

            // batch 2: all 8 rows (independent, guarded; zero-filled if empty)
            int4v vj[8];
#pragma unroll
            for (int j = 0; j < 8; j++) {
                if (s + j < e) vj[j] = *(const int4v*)(hp + (size_t)sj[j] * 256);
                else           vj[j] = (int4v){0, 0, 0, 0};
            }
            // pin: all 8 loads issued (and live) before any accumulate
            __builtin_amdgcn_sched_barrier(0);

            f32x2 c0 = {0.f, 0.f}, c1 = {0.f, 0.f}, c2 = {0.f, 0.f}, c3 = {0.f, 0.f};
#pragma unroll
            for (int j = 0; j < 8; j++) {
                const unsigned int* vu = (const unsigned int*)&vj[j];
                c0 += (f32x2){bflo(vu[0]), bfhi(vu[0])};
                c1 += (f32x2){bflo(vu[1]), bfhi(vu[1])};
                c2 += (f32x2){bflo(vu[2]), bfhi(vu[2])};
                c3 += (f32x2){bflo(vu[3]), bfhi(vu[3])};
            }

            // rare tail: deg > 8
            for (int t = s + 8; t < e; ++t) {
                const int src = csr[t];
                const int4v v = *(const int4v*)(hp + (size_t)src * 256);
                const unsigned int* vu = (const unsigned int*)&v;
                c0 += (f32x2){bflo(vu[0]), bfhi(vu[0])};
                c1 += (f32x2){bflo(vu[1]), bfhi(vu[1])};
                c2 += (f32x2){bflo(vu[2]), bfhi(vu[2])};
                c3 += (f32x2){bflo(vu[3]), bfhi(vu[3])};
            }

            const float inv = 1.0f / fmaxf((float)(e - s), 1.0f);
            unsigned int p0 = (unsigned int)f2bf(inv * c0[0]) | ((unsigned int)f2bf(inv * c0[1]) << 16);
            unsigned int p1 = (unsigned int)f2bf(inv * c1[0]) | ((unsigned int)f2bf(inv * c1[1]) << 16);
            unsigned int p2 = (unsigned int)f2bf(inv * c2[0]) | ((unsigned int)f2bf(inv * c2[1]) << 16);
            unsigned int p3 = (unsigned int)f2bf(inv * c3[0]) | ((unsigned int)f2bf(inv * c3[1]) << 16);
            const int row = (w << 2) + i;
            const int cb = g * 256 + li * 16;
            *(int4v*)(lds + 8192 + row * 1024 + (cb ^ ((row & 7) << 4))) =
                (int4v){(int)p0, (int)p1, (int)p2, (int)p3};
        }
    }

    // ---- B-fragment prefetch for kb=0..3 (independent of LDS; hides under barrier) ----
    const int lr = lane & 15;
    const int lg = lane >> 4;
    const char* bB = (const char*)Bt + (size_t)(w * 16 + lr) * 1280;
    bf16x8 bpre[4];
#pragma unroll
    for (int kb = 0; kb < 4; kb++)
        bpre[kb] = *(const bf16x8*)(bB + kb * 64 + lg * 16);

    __syncthreads();

    // ---- phase 2: GEMM; wave w owns output cols w*16..w*16+16 ----
    f32x4 acc[2];
    acc[0] = (f32x4){0.f, 0.f, 0.f, 0.f};
    acc[1] = (f32x4){0.f, 0.f, 0.f, 0.f};

    __builtin_amdgcn_s_setprio(1);
#pragma unroll
    for (int kb = 0; kb < 20; ++kb) {
        const int kByte = kb * 64 + lg * 16;
        bf16x8 bfr = (kb < 4) ? bpre[kb] : *(const bf16x8*)(bB + kByte);
#pragma unroll
        for (int mi = 0; mi < 2; mi++) {
            const int row = mi * 16 + lr;
            int off;
            if (kb < 4) off = row * 256 + (kByte ^ ((row & 7) << 4));
            else        off = 8192 + row * 1024 + ((kByte - 256) ^ ((row & 7) << 4));
            bf16x8 af = *(const bf16x8*)(lds + off);
            acc[mi] = __builtin_amdgcn_mfma_f32_16x16x32_bf16(af, bfr, acc[mi], 0, 0, 0);
        }
    }
    __builtin_amdgcn_s_setprio(0);

    __syncthreads();                        // all A-reads done; reuse LDS as bounce

    if (MODE == 0) {
        // relu -> bf16 tile [32][256B] at lds[0..8192), XOR-swizzled rows
#pragma unroll
        for (int mi = 0; mi < 2; mi++) {
            const int col = w * 16 + lr;
#pragma unroll
            for (int j = 0; j < 4; j++) {
                const int row = mi * 16 + lg * 4 + j;
                *(unsigned short*)(lds + row * 256 + ((col * 2) ^ ((row & 7) << 4))) =
                    f2bf(fmaxf(acc[mi][j], 0.f));
            }
        }
        __syncthreads();
        unsigned short* o = (unsigned short*)outp;
        const int row = tid >> 4, kb = (tid & 15) * 16;
        const int grow = m0 + row;
        if (grow < M)
            *(int4v*)((char*)o + (size_t)grow * 256 + kb) =
                *(const int4v*)(lds + row * 256 + (kb ^ ((row & 7) << 4)));
    } else {
        // f32 tile [32][512B] at lds[0..16384), XOR-swizzled rows
#pragma unroll
        for (int mi = 0; mi < 2; mi++) {
            const int col = w * 16 + lr;
#pragma unroll
            for (int j = 0; j < 4; j++) {
                const int row = mi * 16 + lg * 4 + j;
                *(float*)(lds + row * 512 + ((col * 4) ^ ((row & 7) << 4))) = acc[mi][j];
            }
        }
        __syncthreads();
        float* o = (float*)outp;
#pragma unroll
        for (int i = 0; i < 2; i++) {
            const int c = tid + i * 512;       // 1024 chunks of 16B
            const int row = c >> 5, o16 = (c & 31) * 16;
            const int grow = m0 + row;
            if (grow < M)
                *(int4v*)((char*)o + (size_t)grow * 512 + o16) =
                    *(const int4v*)(lds + row * 512 + (o16 ^ ((row & 7) << 4)));
        }
    }
}

// ---------------- final gather (float4) ----------------

__global__ __launch_bounds__(256) void gather_out_kernel(const float* __restrict__ hOut,
                                                         const int* __restrict__ head,
                                                         const int* __restrict__ tail,
                                                         float* __restrict__ out) {
    const int gid = blockIdx.x * 256 + threadIdx.x;
    const int q = gid >> 5, c = gid & 31;
    if (q >= 2 * NQ || c >= 25) return;
    const int node = (q < NQ) ? head[q] : tail[q - NQ];
    f32x4 v = *(const f32x4*)(hOut + (size_t)node * 128 + c * 4);
    *(f32x4*)(out + (size_t)q * OD + c * 4) = v;
}

// ---------------- launch ----------------

extern "C" void kernel_launch(void* const* d_in, const int* in_sizes, int n_in,
                              void* d_out, int out_size, void* d_ws, size_t ws_size,
                              hipStream_t stream) {
    const float* feature = (const float*)d_in[0];
    const float* Wr_h    = (const float*)d_in[1];   // [2][4][128][128]
    const float* Ws_h    = (const float*)d_in[2];   // [2][128][128]
    const float* Wr_o    = (const float*)d_in[3];   // [4][128][100]
    const float* Ws_o    = (const float*)d_in[4];   // [128][100]
    const int* edge_src  = (const int*)d_in[5];
    const int* edge_dst  = (const int*)d_in[6];
    const int* head_idx  = (const int*)d_in[7];
    const int* tail_idx  = (const int*)d_in[8];
    float* out = (float*)d_out;

    char* ws = (char*)d_ws;
    size_t off = 0;
    auto alloc = [&](size_t bytes) -> void* {
        void* p = ws + off;
        off += (bytes + 255) & ~(size_t)255;
        return p;
    };
    unsigned short* hA   = (unsigned short*)alloc((size_t)NN * HD * 2);
    unsigned short* hB   = (unsigned short*)alloc((size_t)NN * HD * 2);
    float*          hOut = (float*)alloc((size_t)NN * 128 * 4);
    unsigned short* Wt   = (unsigned short*)alloc((size_t)3 * 128 * 640 * 2);
    int*            deg  = (int*)alloc((size_t)NR * NN * 4);
    int*            rowS = (int*)alloc((size_t)NR * (NN + 1) * 4);
    int*            curs = (int*)alloc((size_t)NR * NN * 4);
    int*            csrS = (int*)alloc((size_t)NR * NE * 4 + 64);
    int*            excl = (int*)alloc((size_t)NR * NN * 4);
    int*            bsum = (int*)alloc((size_t)NR * NB_SCAN * 4);
    (void)ws_size;

    // prep: zero deg, then merged {count_deg | conv_feat | prep_w}
    hipMemsetAsync(deg, 0, (size_t)NR * NN * 4, stream);
    prep_merged_kernel<<<NB_COUNT + NB_CONV + NB_PREPW, 256, 0, stream>>>(
        edge_dst, deg, feature, hA, Ws_h, Wr_h, Ws_o, Wr_o, Wt);
    scanA_kernel<<<NR * NB_SCAN, 256, 0, stream>>>(deg, excl, bsum);
    scanC_kernel<<<NR * NB_SCAN, 256, 0, stream>>>(excl, bsum, rowS, curs);
    fill_csr_kernel<<<NB_COUNT, 256, 0, stream>>>(edge_src, edge_dst, curs, csrS);

    const int fblocks = (NN + 31) / 32;   // 1563
    unsigned short* WtH0 = Wt;
    unsigned short* WtH1 = Wt + 128 * 640;
    unsigned short* WtO  = Wt + 2 * 128 * 640;

    fused_kernel<0><<<fblocks, 512, 0, stream>>>(hA, WtH0, rowS, csrS, hB, NN);
    fused_kernel<0><<<fblocks, 512, 0, stream>>>(hB, WtH1, rowS, csrS, hA, NN);
    fused_kernel<1><<<fblocks, 512, 0, stream>>>(hA, WtO,  rowS, csrS, hOut, NN);

    gather_out_kernel<<<(2 * NQ * 32 + 255) / 256, 256, 0, stream>>>(hOut, head_idx, tail_idx, out);
}

// Round 16
// 220.059 us; speedup vs baseline: 1.9246x; 1.1455x over previous
//
#include <hip/hip_runtime.h>
#include <hip/hip_bf16.h>

#define NN 50000     // nodes
#define NR 4         // relations
#define NE 160000    // edges per relation
#define HD 128       // hidden dim
#define OD 100       // out dim
#define NQ 8192      // queries
#define ELL_CAP 16   // slots per (node, relation); P(deg>16)~1e-8 for Po(3.2)
#define OVF_CAP 8192

// merged-prep region sizes (all exact multiples of 256)
#define NB_BUILD 2500   // NR*NE/256
#define NB_CONV  6250   // NN*HD/4/256
#define NB_PREPW 960    // 3*128*640/256

typedef __attribute__((ext_vector_type(8))) short bf16x8;
typedef __attribute__((ext_vector_type(4))) float f32x4;
typedef __attribute__((ext_vector_type(2))) float f32x2;
typedef __attribute__((ext_vector_type(4))) int int4v;

static __device__ __forceinline__ unsigned short f2bf(float f) {
    union { float f; unsigned int u; } v; v.f = f;
    unsigned int u = v.u;
    unsigned int r = u + 0x7FFFu + ((u >> 16) & 1u);   // RNE
    return (unsigned short)(r >> 16);
}
static __device__ __forceinline__ float bflo(unsigned int v) {
    union { unsigned int u; float f; } x; x.u = v << 16; return x.f;
}
static __device__ __forceinline__ float bfhi(unsigned int v) {
    union { unsigned int u; float f; } x; x.u = v & 0xffff0000u; return x.f;
}

// ------- merged prep: build_ell | conv_feat | prep_w  (one pass, no scan) -------
// deg[key] (key = dst*4+r) doubles as the ELL insertion cursor: after this
// kernel deg[key] == true degree; slots 0..min(deg,16)-1 of ell[key][*] hold
// the sources; edges past 16 land in the overflow side-list (ovf, ovf_cnt).

__global__ __launch_bounds__(256) void prep_merged_kernel(
        const int* __restrict__ edge_src, const int* __restrict__ edge_dst,
        int* __restrict__ deg, int* __restrict__ ell,
        int* __restrict__ ovf_cnt, int2* __restrict__ ovf,
        const float* __restrict__ feature, unsigned short* __restrict__ h,
        const float* __restrict__ Ws_h, const float* __restrict__ Wr_h,
        const float* __restrict__ Ws_o, const float* __restrict__ Wr_o,
        unsigned short* __restrict__ Wt) {
    const int b = blockIdx.x;
    if (b < NB_BUILD) {
        const int i = b * 256 + threadIdx.x;            // < NR*NE exactly
        const int r = i / NE;
        const int key = (edge_dst[i] << 2) | r;
        const int src = edge_src[i];
        const int pos = atomicAdd(&deg[key], 1);
        if (pos < ELL_CAP) ell[key * ELL_CAP + pos] = src;
        else {
            const int op = atomicAdd(ovf_cnt, 1);
            if (op < OVF_CAP) ovf[op] = make_int2(key, src);
        }
    } else if (b < NB_BUILD + NB_CONV) {
        const int i = ((b - NB_BUILD) * 256 + threadIdx.x) * 4;  // < NN*HD exactly
        h[i + 0] = f2bf(feature[i + 0]);
        h[i + 1] = f2bf(feature[i + 1]);
        h[i + 2] = f2bf(feature[i + 2]);
        h[i + 3] = f2bf(feature[i + 3]);
    } else {
        const int idx = (b - NB_BUILD - NB_CONV) * 256 + threadIdx.x;  // < 3*128*640
        const int l = idx / (128 * 640);
        const int rem = idx % (128 * 640);
        const int c = rem / 640;
        const int k = rem % 640;
        float v = 0.0f;
        if (l < 2) {
            if (k < HD) v = Ws_h[(l * HD + k) * HD + c];
            else {
                int r = (k - HD) >> 7, kk = (k - HD) & 127;
                v = Wr_h[((l * NR + r) * HD + kk) * HD + c];
            }
        } else if (c < OD) {
            if (k < HD) v = Ws_o[k * OD + c];
            else {
                int r = (k - HD) >> 7, kk = (k - HD) & 127;
                v = Wr_o[(r * HD + kk) * OD + c];
            }
        }
        Wt[idx] = f2bf(v);
    }
}

// ---------------- fused: ELL 8-slot batched reg-gather + GEMM ----------------
// Block = 512 thr (8 waves), 32 nodes. LDS 40KB: [0,8192) hT ; [8192,40960) agg.
// Phase 0: stage h tile [32][256B] -> LDS (swizzled), 1 x 16B per thread.
// Phase 1: wave w handles nodes 4w..4w+3; lane-group g (16 lanes x 16B = full
//          256B h row) = relation g. Per (node,rel): one uniform deg load,
//          2 x dwordx4 slot loads (8 srcs), 8 guarded h-row loads (8-deep
//          MLP), packed f32x2 accumulate; rare second 8-slot batch for
//          deg 9..16; overflow side-list scan for deg > 16 (~never).
//          Scale by 1/max(deg,1); one swizzled ds_write_b128. No scan/CSR.
// Phase 2: GEMM [hT | agg](32x640) @ Wt(128x640)^T. Wave w owns 16 cols;
//          B frags kb<4 prefetched pre-barrier; A from LDS (XOR swizzle);
//          20 K-steps, setprio(1) around the MFMA loop.
// Epilogues: XOR-swizzled LDS bounce (conflict-free), coalesced 16B stores.

template<int MODE>
__global__ __launch_bounds__(512, 8)
void fused_kernel(const unsigned short* __restrict__ h,
                  const unsigned short* __restrict__ Bt,
                  const int* __restrict__ deg,
                  const int* __restrict__ ell,
                  const int* __restrict__ ovf_cnt,
                  const int2* __restrict__ ovf,
                  void* __restrict__ outp, int M) {
    __shared__ __align__(16) char lds[40960];   // [0,8192) hT ; [8192,40960) agg
    const int tid = threadIdx.x;
    const int m0 = blockIdx.x * 32;
    const int lane = tid & 63;
    const int w = tid >> 6;            // 0..7

    // ---- phase 0: stage h tile ----
    {
        const int row = tid >> 4, kb = (tid & 15) * 16;
        int gr = m0 + row; if (gr >= M) gr = M - 1;
        int4v v = *(const int4v*)((const char*)h + (size_t)gr * 256 + kb);
        *(int4v*)(lds + row * 256 + (kb ^ ((row & 7) << 4))) = v;
    }

    // ---- phase 1: ELL batched gather ----
    {
        const int g = lane >> 4, li = lane & 15;
        const char* hp = (const char*)h + li * 16;
        const int n0 = m0 + (w << 2);

#pragma unroll 1
        for (int i = 0; i < 4; ++i) {
            const int n = n0 + i;
            const int nc = (n < M) ? n : (M - 1);
            const int key = (nc << 2) | g;
            const int dg = (n < M) ? deg[key] : 0;
            const int e = (dg < ELL_CAP) ? dg : ELL_CAP;
            const int* eb = ell + ((size_t)key << 4);

            // slots 0-7: two dwordx4 loads (unguarded reads of allocated ws)
            const int4v s03 = *(const int4v*)(eb);
            const int4v s47 = *(const int4v*)(eb + 4);

            // rows 0-7 (guarded, independent; zero-filled if empty)
            int4v vj[8];
            const int4v z = {0, 0, 0, 0};
#pragma unroll
            for (int j = 0; j < 4; j++)
                vj[j] = (j < e) ? *(const int4v*)(hp + (size_t)s03[j] * 256) : z;
#pragma unroll
            for (int j = 0; j < 4; j++)
                vj[4 + j] = (4 + j < e) ? *(const int4v*)(hp + (size_t)s47[j] * 256) : z;
            __builtin_amdgcn_sched_barrier(0);

            f32x2 c0 = {0.f, 0.f}, c1 = {0.f, 0.f}, c2 = {0.f, 0.f}, c3 = {0.f, 0.f};
#pragma unroll
            for (int j = 0; j < 8; j++) {
                const unsigned int* vu = (const unsigned int*)&vj[j];
                c0 += (f32x2){bflo(vu[0]), bfhi(vu[0])};
                c1 += (f32x2){bflo(vu[1]), bfhi(vu[1])};
                c2 += (f32x2){bflo(vu[2]), bfhi(vu[2])};
                c3 += (f32x2){bflo(vu[3]), bfhi(vu[3])};
            }

            // rare: slots 8-15 (deg 9..16)
            if (dg > 8) {
                const int4v s8  = *(const int4v*)(eb + 8);
                const int4v s12 = *(const int4v*)(eb + 12);
                int4v wj[8];
#pragma unroll
                for (int j = 0; j < 4; j++)
                    wj[j] = (8 + j < e) ? *(const int4v*)(hp + (size_t)s8[j] * 256) : z;
#pragma unroll
                for (int j = 0; j < 4; j++)
                    wj[4 + j] = (12 + j < e) ? *(const int4v*)(hp + (size_t)s12[j] * 256) : z;
#pragma unroll
                for (int j = 0; j < 8; j++) {
                    const unsigned int* vu = (const unsigned int*)&wj[j];
                    c0 += (f32x2){bflo(vu[0]), bfhi(vu[0])};
                    c1 += (f32x2){bflo(vu[1]), bfhi(vu[1])};
                    c2 += (f32x2){bflo(vu[2]), bfhi(vu[2])};
                    c3 += (f32x2){bflo(vu[3]), bfhi(vu[3])};
                }
            }

            // safety net: deg > 16 -> scan tiny overflow side-list (~never taken)
            if (dg > ELL_CAP) {
                int oc = ovf_cnt[0];
                if (oc > OVF_CAP) oc = OVF_CAP;
                for (int k = 0; k < oc; ++k) {
                    const int2 ov = ovf[k];
                    if (ov.x == key) {
                        const int4v v = *(const int4v*)(hp + (size_t)ov.y * 256);
                        const unsigned int* vu = (const unsigned int*)&v;
                        c0 += (f32x2){bflo(vu[0]), bfhi(vu[0])};
                        c1 += (f32x2){bflo(vu[1]), bfhi(vu[1])};
                        c2 += (f32x2){bflo(vu[2]), bfhi(vu[2])};
                        c3 += (f32x2){bflo(vu[3]), bfhi(vu[3])};
                    }
                }
            }

            const float inv = 1.0f / fmaxf((float)dg, 1.0f);
            unsigned int p0 = (unsigned int)f2bf(inv * c0[0]) | ((unsigned int)f2bf(inv * c0[1]) << 16);
            unsigned int p1 = (unsigned int)f2bf(inv * c1[0]) | ((unsigned int)f2bf(inv * c1[1]) << 16);
            unsigned int p2 = (unsigned int)f2bf(inv * c2[0]) | ((unsigned int)f2bf(inv * c2[1]) << 16);
            unsigned int p3 = (unsigned int)f2bf(inv * c3[0]) | ((unsigned int)f2bf(inv * c3[1]) << 16);
            const int row = (w << 2) + i;
            const int cb = g * 256 + li * 16;
            *(int4v*)(lds + 8192 + row * 1024 + (cb ^ ((row & 7) << 4))) =
                (int4v){(int)p0, (int)p1, (int)p2, (int)p3};
        }
    }

    // ---- B-fragment prefetch for kb=0..3 (independent of LDS; hides under barrier) ----
    const int lr = lane & 15;
    const int lg = lane >> 4;
    const char* bB = (const char*)Bt + (size_t)(w * 16 + lr) * 1280;
    bf16x8 bpre[4];
#pragma unroll
    for (int kb = 0; kb < 4; kb++)
        bpre[kb] = *(const bf16x8*)(bB + kb * 64 + lg * 16);

    __syncthreads();

    // ---- phase 2: GEMM; wave w owns output cols w*16..w*16+16 ----
    f32x4 acc[2];
    acc[0] = (f32x4){0.f, 0.f, 0.f, 0.f};
    acc[1] = (f32x4){0.f, 0.f, 0.f, 0.f};

    __builtin_amdgcn_s_setprio(1);
#pragma unroll
    for (int kb = 0; kb < 20; ++kb) {
        const int kByte = kb * 64 + lg * 16;
        bf16x8 bfr = (kb < 4) ? bpre[kb] : *(const bf16x8*)(bB + kByte);
#pragma unroll
        for (int mi = 0; mi < 2; mi++) {
            const int row = mi * 16 + lr;
            int off;
            if (kb < 4) off = row * 256 + (kByte ^ ((row & 7) << 4));
            else        off = 8192 + row * 1024 + ((kByte - 256) ^ ((row & 7) << 4));
            bf16x8 af = *(const bf16x8*)(lds + off);
            acc[mi] = __builtin_amdgcn_mfma_f32_16x16x32_bf16(af, bfr, acc[mi], 0, 0, 0);
        }
    }
    __builtin_amdgcn_s_setprio(0);

    __syncthreads();                        // all A-reads done; reuse LDS as bounce

    if (MODE == 0) {
        // relu -> bf16 tile [32][256B] at lds[0..8192), XOR-swizzled rows
#pragma unroll
        for (int mi = 0; mi < 2; mi++) {
            const int col = w * 16 + lr;
#pragma unroll
            for (int j = 0; j < 4; j++) {
                const int row = mi * 16 + lg * 4 + j;
                *(unsigned short*)(lds + row * 256 + ((col * 2) ^ ((row & 7) << 4))) =
                    f2bf(fmaxf(acc[mi][j], 0.f));
            }
        }
        __syncthreads();
        unsigned short* o = (unsigned short*)outp;
        const int row = tid >> 4, kb = (tid & 15) * 16;
        const int grow = m0 + row;
        if (grow < M)
            *(int4v*)((char*)o + (size_t)grow * 256 + kb) =
                *(const int4v*)(lds + row * 256 + (kb ^ ((row & 7) << 4)));
    } else {
        // f32 tile [32][512B] at lds[0..16384), XOR-swizzled rows
#pragma unroll
        for (int mi = 0; mi < 2; mi++) {
            const int col = w * 16 + lr;
#pragma unroll
            for (int j = 0; j < 4; j++) {
                const int row = mi * 16 + lg * 4 + j;
                *(float*)(lds + row * 512 + ((col * 4) ^ ((row & 7) << 4))) = acc[mi][j];
            }
        }
        __syncthreads();
        float* o = (float*)outp;
#pragma unroll
        for (int i = 0; i < 2; i++) {
            const int c = tid + i * 512;       // 1024 chunks of 16B
            const int row = c >> 5, o16 = (c & 31) * 16;
            const int grow = m0 + row;
            if (grow < M)
                *(int4v*)((char*)o + (size_t)grow * 512 + o16) =
                    *(const int4v*)(lds + row * 512 + (o16 ^ ((row & 7) << 4)));
        }
    }
}

// ---------------- final gather (float4) ----------------

__global__ __launch_bounds__(256) void gather_out_kernel(const float* __restrict__ hOut,
                                                         const int* __restrict__ head,
                                                         const int* __restrict__ tail,
                                                         float* __restrict__ out) {
    const int gid = blockIdx.x * 256 + threadIdx.x;
    const int q = gid >> 5, c = gid & 31;
    if (q >= 2 * NQ || c >= 25) return;
    const int node = (q < NQ) ? head[q] : tail[q - NQ];
    f32x4 v = *(const f32x4*)(hOut + (size_t)node * 128 + c * 4);
    *(f32x4*)(out + (size_t)q * OD + c * 4) = v;
}

// ---------------- launch ----------------

extern "C" void kernel_launch(void* const* d_in, const int* in_sizes, int n_in,
                              void* d_out, int out_size, void* d_ws, size_t ws_size,
                              hipStream_t stream) {
    const float* feature = (const float*)d_in[0];
    const float* Wr_h    = (const float*)d_in[1];   // [2][4][128][128]
    const float* Ws_h    = (const float*)d_in[2];   // [2][128][128]
    const float* Wr_o    = (const float*)d_in[3];   // [4][128][100]
    const float* Ws_o    = (const float*)d_in[4];   // [128][100]
    const int* edge_src  = (const int*)d_in[5];
    const int* edge_dst  = (const int*)d_in[6];
    const int* head_idx  = (const int*)d_in[7];
    const int* tail_idx  = (const int*)d_in[8];
    float* out = (float*)d_out;

    char* ws = (char*)d_ws;
    size_t off = 0;
    auto alloc = [&](size_t bytes) -> void* {
        void* p = ws + off;
        off += (bytes + 255) & ~(size_t)255;
        return p;
    };
    unsigned short* hA   = (unsigned short*)alloc((size_t)NN * HD * 2);
    unsigned short* hB   = (unsigned short*)alloc((size_t)NN * HD * 2);
    float*          hOut = (float*)alloc((size_t)NN * 128 * 4);
    unsigned short* Wt   = (unsigned short*)alloc((size_t)3 * 128 * 640 * 2);
    int*            deg  = (int*)alloc((size_t)NR * NN * 4);          // 800000 B (contig
    int*            ovfc = (int*)alloc(256);                          //  with ovfc)
    int*            ell  = (int*)alloc((size_t)NR * NN * ELL_CAP * 4);
    int2*           ovf  = (int2*)alloc((size_t)OVF_CAP * 8);
    (void)ws_size;

    // prep: zero deg+ovfc (contiguous), then ONE merged pass {build_ell | conv_feat | prep_w}
    hipMemsetAsync(deg, 0, (size_t)NR * NN * 4 + 256, stream);
    prep_merged_kernel<<<NB_BUILD + NB_CONV + NB_PREPW, 256, 0, stream>>>(
        edge_src, edge_dst, deg, ell, ovfc, ovf,
        feature, hA, Ws_h, Wr_h, Ws_o, Wr_o, Wt);

    const int fblocks = (NN + 31) / 32;   // 1563
    unsigned short* WtH0 = Wt;
    unsigned short* WtH1 = Wt + 128 * 640;
    unsigned short* WtO  = Wt + 2 * 128 * 640;

    fused_kernel<0><<<fblocks, 512, 0, stream>>>(hA, WtH0, deg, ell, ovfc, ovf, hB, NN);
    fused_kernel<0><<<fblocks, 512, 0, stream>>>(hB, WtH1, deg, ell, ovfc, ovf, hA, NN);
    fused_kernel<1><<<fblocks, 512, 0, stream>>>(hA, WtO,  deg, ell, ovfc, ovf, hOut, NN);

    gather_out_kernel<<<(2 * NQ * 32 + 255) / 256, 256, 0, stream>>>(hOut, head_idx, tail_idx, out);
}